// Round 2
// baseline (870.233 us; speedup 1.0000x reference)
//
#include <hip/hip_runtime.h>

// Problem constants (fixed by the reference)
#define B_    128
#define L_    1024
#define DK_   128
#define DV_   256
#define NS_   50      // N memory slots
#define H_    256
#define M_    (B_ * L_)   // 131072 rows

typedef __attribute__((ext_vector_type(8))) short   short8;
typedef __attribute__((ext_vector_type(4))) float   float4v;
typedef __attribute__((ext_vector_type(4))) int     int4v;

__device__ __forceinline__ float b2f(unsigned short u) {
    unsigned int x = ((unsigned int)u) << 16;
    return __builtin_bit_cast(float, x);
}
__device__ __forceinline__ unsigned short f2b(float f) {
    unsigned int x = __builtin_bit_cast(unsigned int, f);
    x += 0x7fffu + ((x >> 16) & 1u);   // round-to-nearest-even
    return (unsigned short)(x >> 16);
}
__device__ __forceinline__ int pack2(float lo, float hi) {
    return (int)f2b(lo) | ((int)f2b(hi) << 16);
}
__device__ __forceinline__ float sigmoid_f(float x) {
    return 1.f / (1.f + __expf(-x));
}
__device__ __forceinline__ float tanh_f(float x) {
    return 1.f - 2.f / (__expf(2.f * x) + 1.f);  // safe at exp overflow
}

// async global -> LDS, 16B per lane (wave-uniform LDS base; HW adds lane*16)
__device__ __forceinline__ void gload_lds16(const void* g, void* l) {
    __builtin_amdgcn_global_load_lds(
        (const __attribute__((address_space(1))) void*)g,
        (__attribute__((address_space(3))) void*)l, 16, 0, 0);
}

// ---------------------------------------------------------------------------
// Gate kernel: e = sigmoid(X We^T + be), a = tanh(X Wa^T + ba)
// X: (M_,256) fp32. We/Wa: (256,256) fp32 row-major [out][in] = B^T layout.
// Outputs bf16. grid (M_/128, 2, 2)  block 256
// ---------------------------------------------------------------------------
__global__ __launch_bounds__(256) void gate_kernel(
    const float* __restrict__ X,
    const float* __restrict__ We, const float* __restrict__ be,
    const float* __restrict__ Wa, const float* __restrict__ ba,
    unsigned short* __restrict__ e_out, unsigned short* __restrict__ a_out)
{
    constexpr int K = DV_;  // 256
    const int mblk = blockIdx.x, nblk = blockIdx.y, gate = blockIdx.z;
    const float* W    = gate ? Wa : We;
    const float* bias = gate ? ba : be;
    unsigned short* out = gate ? a_out : e_out;

    __shared__ unsigned short As[128 * 40];  // +8 pad per row
    __shared__ unsigned short Bs[128 * 40];

    const int tid  = threadIdx.x;
    const int lane = tid & 63, wid = tid >> 6;
    const int wm = wid >> 1, wn = wid & 1;
    const int l15 = lane & 15, quad = lane >> 4;

    float4v acc[4][4];
#pragma unroll
    for (int i = 0; i < 4; i++)
#pragma unroll
        for (int j = 0; j < 4; j++) {
            acc[i][j][0] = 0.f; acc[i][j][1] = 0.f;
            acc[i][j][2] = 0.f; acc[i][j][3] = 0.f;
        }

    const int srow = tid >> 1;          // 0..127
    const int scol = (tid & 1) * 16;    // 0 or 16 (bf16 element units)
    const size_t Abase = ((size_t)mblk * 128 + srow) * K;
    const size_t Bbase = ((size_t)nblk * 128 + srow) * K;

    for (int k0 = 0; k0 < K; k0 += 32) {
        const float* xa = &X[Abase + k0 + scol];
        const float* xb = &W[Bbase + k0 + scol];
        // vectorized fp32 loads (dwordx4), then pack to bf16
        float4v va0 = *(const float4v*)(xa);
        float4v va1 = *(const float4v*)(xa + 4);
        float4v va2 = *(const float4v*)(xa + 8);
        float4v va3 = *(const float4v*)(xa + 12);
        float4v vb0 = *(const float4v*)(xb);
        float4v vb1 = *(const float4v*)(xb + 4);
        float4v vb2 = *(const float4v*)(xb + 8);
        float4v vb3 = *(const float4v*)(xb + 12);
        int4v pa0, pa1, pb0, pb1;
        pa0[0] = pack2(va0[0], va0[1]); pa0[1] = pack2(va0[2], va0[3]);
        pa0[2] = pack2(va1[0], va1[1]); pa0[3] = pack2(va1[2], va1[3]);
        pa1[0] = pack2(va2[0], va2[1]); pa1[1] = pack2(va2[2], va2[3]);
        pa1[2] = pack2(va3[0], va3[1]); pa1[3] = pack2(va3[2], va3[3]);
        pb0[0] = pack2(vb0[0], vb0[1]); pb0[1] = pack2(vb0[2], vb0[3]);
        pb0[2] = pack2(vb1[0], vb1[1]); pb0[3] = pack2(vb1[2], vb1[3]);
        pb1[0] = pack2(vb2[0], vb2[1]); pb1[1] = pack2(vb2[2], vb2[3]);
        pb1[2] = pack2(vb3[0], vb3[1]); pb1[3] = pack2(vb3[2], vb3[3]);
        *(int4v*)&As[srow * 40 + scol]     = pa0;
        *(int4v*)&As[srow * 40 + scol + 8] = pa1;
        *(int4v*)&Bs[srow * 40 + scol]     = pb0;
        *(int4v*)&Bs[srow * 40 + scol + 8] = pb1;
        __syncthreads();
        short8 af[4], bf[4];
#pragma unroll
        for (int i = 0; i < 4; i++)
            af[i] = *(const short8*)&As[(64 * wm + 16 * i + l15) * 40 + quad * 8];
#pragma unroll
        for (int j = 0; j < 4; j++)
            bf[j] = *(const short8*)&Bs[(64 * wn + 16 * j + l15) * 40 + quad * 8];
#pragma unroll
        for (int i = 0; i < 4; i++)
#pragma unroll
            for (int j = 0; j < 4; j++)
                acc[i][j] = __builtin_amdgcn_mfma_f32_16x16x32_bf16(af[i], bf[j], acc[i][j], 0, 0, 0);
        __syncthreads();
    }

#pragma unroll
    for (int i = 0; i < 4; i++) {
        const int row = mblk * 128 + 64 * wm + 16 * i + quad * 4;
#pragma unroll
        for (int j = 0; j < 4; j++) {
            const int col = nblk * 128 + 64 * wn + 16 * j + l15;
            const float bv = bias[col];
#pragma unroll
            for (int r = 0; r < 4; r++) {
                float v = acc[i][j][r] + bv;
                v = gate ? tanh_f(v) : sigmoid_f(v);
                out[(size_t)(row + r) * DV_ + col] = f2b(v);
            }
        }
    }
}

// ---------------------------------------------------------------------------
// Score kernel: score = softmax(P Wk^T) over 50 slots. Thread per row. fp32.
// Direct layout: (M_,64) fp32, column n = softmax slot n for n<50, 0 else.
// grid 512, block 256
// ---------------------------------------------------------------------------
__global__ __launch_bounds__(256) void score_kernel(
    const float* __restrict__ problems,  // (M_,128)
    const float* __restrict__ w_key,     // (50,128)
    float* __restrict__ score_scan)      // (M_,64)
{
    const int rowi = blockIdx.x * 256 + threadIdx.x;
    const float* p = problems + (size_t)rowi * DK_;

    float logit[NS_];
#pragma unroll
    for (int n = 0; n < NS_; n++) logit[n] = 0.f;

    for (int k0 = 0; k0 < DK_; k0 += 4) {
        float pf0 = p[k0], pf1 = p[k0+1], pf2 = p[k0+2], pf3 = p[k0+3];
#pragma unroll
        for (int n = 0; n < NS_; n++) {
            const float* wk = &w_key[n * DK_ + k0];   // wave-uniform -> s_load
            logit[n] += pf0 * wk[0] + pf1 * wk[1] + pf2 * wk[2] + pf3 * wk[3];
        }
    }

    float mx = logit[0];
#pragma unroll
    for (int n = 1; n < NS_; n++) mx = fmaxf(mx, logit[n]);
    float sum = 0.f;
#pragma unroll
    for (int n = 0; n < NS_; n++) { logit[n] = __expf(logit[n] - mx); sum += logit[n]; }
    const float inv = 1.f / sum;

    float* o = score_scan + (size_t)rowi * 64;
#pragma unroll
    for (int v = 0; v < 16; v++) {
        float4v st;
#pragma unroll
        for (int c = 0; c < 4; c++) {
            const int j = v * 4 + c;
            st[c] = (j < NS_) ? logit[j] * inv : 0.f;
        }
        *(float4v*)(o + v * 4) = st;
    }
}

// ---------------------------------------------------------------------------
// Scan kernel v4: 8 lanes per (b,d) pair, 8 slots/lane (direct slot mapping,
// slots 50..63 zero-padded). Chunked double-buffered LDS staging via
// global_load_lds. Block = 4 waves covers 32 d-columns.
// LDS: 2 x (32t x 256B score + 32t x 64B e + 32t x 64B a) = 24 KB.
// grid (8, 128)  block 256  -> 4 blocks/CU, 16 waves/CU.
// ---------------------------------------------------------------------------
#define TCH 32
#define NCH (L_ / TCH)   // 32

__global__ __launch_bounds__(256, 4) void scan_kernel(
    const float* __restrict__ score_scan,         // (M_,64) fp32, zero-padded
    const unsigned short* __restrict__ e_buf,     // (M_,256) bf16
    const unsigned short* __restrict__ a_buf,     // (M_,256) bf16
    const float* __restrict__ init_mem,           // (50,256) fp32
    unsigned short* __restrict__ reads)           // (M_,256) bf16
{
    __shared__ float          score_s[2][TCH][64];   // 2 x 8 KB
    __shared__ unsigned short e_s[2][TCH][32];       // 2 x 2 KB
    __shared__ unsigned short a_s[2][TCH][32];       // 2 x 2 KB

    const int b    = blockIdx.y;
    const int dblk = blockIdx.x;          // 0..7
    const int tid  = threadIdx.x;
    const int w    = tid >> 6;
    const int lane = tid & 63;
    const int dsub = lane & 7;            // d sub-index within wave
    const int ng   = lane >> 3;           // slot group 0..7
    const int dcol = w * 8 + dsub;        // 0..31 within block
    const int d    = dblk * 32 + dcol;

    float M[8];
#pragma unroll
    for (int i = 0; i < 8; i++) {
        const int n = ng * 8 + i;
        M[i] = (n < NS_) ? init_mem[n * DV_ + d] : 0.f;
    }

    const size_t rb = (size_t)b * L_;

    auto stage = [&](int c, int p) {
        const int t0 = c * TCH;
        // score: 32 rows x 256B = 8KB -> 2 insts/wave (1KB = 4 rows each)
        // lane: row_local = lane>>4, col = (lane&15)*4 floats
#pragma unroll
        for (int i = 0; i < 2; i++) {
            const int tt = t0 + w * 8 + i * 4 + (lane >> 4);
            gload_lds16(score_scan + ((rb + tt) * 64 + (lane & 15) * 4),
                        &score_s[p][w * 8 + i * 4][0]);
        }
        // e/a: 32 rows x 64B = 2KB each -> waves 0,1 stage e; waves 2,3 stage a
        // per inst: 16 rows, lane: row_local = lane>>2, col = (lane&3)*8 shorts
        if (w < 2) {
            const int tt = t0 + w * 16 + (lane >> 2);
            gload_lds16(e_buf + ((rb + tt) * DV_ + dblk * 32 + (lane & 3) * 8),
                        &e_s[p][w * 16][0]);
        } else {
            const int tt = t0 + (w - 2) * 16 + (lane >> 2);
            gload_lds16(a_buf + ((rb + tt) * DV_ + dblk * 32 + (lane & 3) * 8),
                        &a_s[p][(w - 2) * 16][0]);
        }
    };

    unsigned short* rp = reads + rb * DV_ + d;

    int p = 0;
    stage(0, 0);
    asm volatile("s_waitcnt vmcnt(0)" ::: "memory");
    __syncthreads();

    for (int c = 0; c < NCH; ++c) {
        if (c + 1 < NCH) stage(c + 1, p ^ 1);   // in flight during compute

#pragma unroll 4
        for (int tt = 0; tt < TCH; ++tt) {
            const float* sc = &score_s[p][tt][ng * 8];
            const float4v s0 = *(const float4v*)(sc);
            const float4v s1 = *(const float4v*)(sc + 4);
            const float e_cur = b2f(e_s[p][tt][dcol]);
            const float a_cur = b2f(a_s[p][tt][dcol]);

            float r = 0.f;
            const float sarr[8] = { s0[0], s0[1], s0[2], s0[3],
                                    s1[0], s1[1], s1[2], s1[3] };
#pragma unroll
            for (int i = 0; i < 8; i++) {
                const float s = sarr[i];
                r = fmaf(s, M[i], r);                       // read BEFORE update
                M[i] = fmaf(s, fmaf(-e_cur, M[i], a_cur), M[i]);
            }
            // reduce partial reads across the 8 slot-groups (lane bits 3,4,5)
            r += __shfl_xor(r, 8);
            r += __shfl_xor(r, 16);
            r += __shfl_xor(r, 32);
            if (ng == 0) rp[(size_t)(c * TCH + tt) * DV_] = f2b(r);
        }

        asm volatile("s_waitcnt vmcnt(0)" ::: "memory");  // next chunk landed
        __syncthreads();                                  // all waves done with buf p
        p ^= 1;
    }
}

// ---------------------------------------------------------------------------
// Output kernel: out = tanh([reads | problems] Wo^T + bo), fp32 out
// K = 384 (256 reads bf16 + 128 problems fp32). grid (M_/128, 2) block 256
// ---------------------------------------------------------------------------
__global__ __launch_bounds__(256) void out_kernel(
    const unsigned short* __restrict__ reads,  // (M_,256) bf16
    const float* __restrict__ problems,        // (M_,128) fp32
    const float* __restrict__ Wo,              // (256,384) fp32
    const float* __restrict__ bo,              // (256) fp32
    float* __restrict__ out)                   // (M_,256) fp32
{
    constexpr int K = DV_ + DK_;  // 384
    const int mblk = blockIdx.x, nblk = blockIdx.y;

    __shared__ unsigned short As[128 * 40];
    __shared__ unsigned short Bs[128 * 40];

    const int tid  = threadIdx.x;
    const int lane = tid & 63, wid = tid >> 6;
    const int wm = wid >> 1, wn = wid & 1;
    const int l15 = lane & 15, quad = lane >> 4;

    float4v acc[4][4];
#pragma unroll
    for (int i = 0; i < 4; i++)
#pragma unroll
        for (int j = 0; j < 4; j++) {
            acc[i][j][0] = 0.f; acc[i][j][1] = 0.f;
            acc[i][j][2] = 0.f; acc[i][j][3] = 0.f;
        }

    const int srow = tid >> 1;
    const int scol = (tid & 1) * 16;
    const size_t mrow = (size_t)mblk * 128 + srow;
    const size_t brow = (size_t)nblk * 128 + srow;

    for (int k0 = 0; k0 < K; k0 += 32) {
        const int kk = k0 + scol;
        int4v a0, a1;
        if (kk < DV_) {  // reads, already bf16
            a0 = *(const int4v*)&reads[mrow * DV_ + kk];
            a1 = *(const int4v*)&reads[mrow * DV_ + kk + 8];
        } else {         // problems, fp32 -> bf16 (vectorized loads)
            const float* pr = &problems[mrow * DK_ + (kk - DV_)];
            float4v v0 = *(const float4v*)(pr);
            float4v v1 = *(const float4v*)(pr + 4);
            float4v v2 = *(const float4v*)(pr + 8);
            float4v v3 = *(const float4v*)(pr + 12);
            a0[0] = pack2(v0[0], v0[1]); a0[1] = pack2(v0[2], v0[3]);
            a0[2] = pack2(v1[0], v1[1]); a0[3] = pack2(v1[2], v1[3]);
            a1[0] = pack2(v2[0], v2[1]); a1[1] = pack2(v2[2], v2[3]);
            a1[2] = pack2(v3[0], v3[1]); a1[3] = pack2(v3[2], v3[3]);
        }
        const float* wb = &Wo[brow * K + kk];
        float4v u0 = *(const float4v*)(wb);
        float4v u1 = *(const float4v*)(wb + 4);
        float4v u2 = *(const float4v*)(wb + 8);
        float4v u3 = *(const float4v*)(wb + 12);
        int4v b0, b1;
        b0[0] = pack2(u0[0], u0[1]); b0[1] = pack2(u0[2], u0[3]);
        b0[2] = pack2(u1[0], u1[1]); b0[3] = pack2(u1[2], u1[3]);
        b1[0] = pack2(u2[0], u2[1]); b1[1] = pack2(u2[2], u2[3]);
        b1[2] = pack2(u3[0], u3[1]); b1[3] = pack2(u3[2], u3[3]);
        *(int4v*)&As[srow * 40 + scol]     = a0;
        *(int4v*)&As[srow * 40 + scol + 8] = a1;
        *(int4v*)&Bs[srow * 40 + scol]     = b0;
        *(int4v*)&Bs[srow * 40 + scol + 8] = b1;
        __syncthreads();
        short8 af[4], bf[4];
#pragma unroll
        for (int i = 0; i < 4; i++)
            af[i] = *(const short8*)&As[(64 * wm + 16 * i + l15) * 40 + quad * 8];
#pragma unroll
        for (int j = 0; j < 4; j++)
            bf[j] = *(const short8*)&Bs[(64 * wn + 16 * j + l15) * 40 + quad * 8];
#pragma unroll
        for (int i = 0; i < 4; i++)
#pragma unroll
            for (int j = 0; j < 4; j++)
                acc[i][j] = __builtin_amdgcn_mfma_f32_16x16x32_bf16(af[i], bf[j], acc[i][j], 0, 0, 0);
        __syncthreads();
    }

#pragma unroll
    for (int i = 0; i < 4; i++) {
        const int row = mblk * 128 + 64 * wm + 16 * i + quad * 4;
#pragma unroll
        for (int j = 0; j < 4; j++) {
            const int col = nblk * 128 + 64 * wn + 16 * j + l15;
            const float bv = bo[col];
#pragma unroll
            for (int r = 0; r < 4; r++) {
                out[(size_t)(row + r) * H_ + col] = tanh_f(acc[i][j][r] + bv);
            }
        }
    }
}

// ---------------------------------------------------------------------------
extern "C" void kernel_launch(void* const* d_in, const int* in_sizes, int n_in,
                              void* d_out, int out_size, void* d_ws, size_t ws_size,
                              hipStream_t stream) {
    const float* problems  = (const float*)d_in[0];
    const float* interact  = (const float*)d_in[1];
    const float* w_key     = (const float*)d_in[2];
    const float* w_erase_w = (const float*)d_in[3];
    const float* w_erase_b = (const float*)d_in[4];
    const float* w_add_w   = (const float*)d_in[5];
    const float* w_add_b   = (const float*)d_in[6];
    const float* w_out_w   = (const float*)d_in[7];
    const float* w_out_b   = (const float*)d_in[8];
    const float* init_mem  = (const float*)d_in[9];

    // workspace: e (64MB bf16) | a (64MB bf16) | reads (64MB bf16) | score_scan (33.5MB fp32)
    char* ws = (char*)d_ws;
    const size_t SZ_BF = (size_t)M_ * DV_ * 2;   // 67,108,864
    unsigned short* e_buf = (unsigned short*)(ws);
    unsigned short* a_buf = (unsigned short*)(ws + SZ_BF);
    unsigned short* reads = (unsigned short*)(ws + 2 * SZ_BF);
    float*     score_scan = (float*)(ws + 3 * SZ_BF);

    gate_kernel<<<dim3(M_ / 128, DV_ / 128, 2), 256, 0, stream>>>(
        interact, w_erase_w, w_erase_b, w_add_w, w_add_b, e_buf, a_buf);

    score_kernel<<<M_ / 256, 256, 0, stream>>>(problems, w_key, score_scan);

    scan_kernel<<<dim3(8, B_), 256, 0, stream>>>(
        score_scan, e_buf, a_buf, init_mem, reads);

    out_kernel<<<dim3(M_ / 128, H_ / 128), 256, 0, stream>>>(
        reads, problems, w_out_w, w_out_b, (float*)d_out);
}

// Round 3
// 854.349 us; speedup vs baseline: 1.0186x; 1.0186x over previous
//
#include <hip/hip_runtime.h>

// Problem constants (fixed by the reference)
#define B_    128
#define L_    1024
#define DK_   128
#define DV_   256
#define NS_   50      // N memory slots
#define H_    256
#define M_    (B_ * L_)   // 131072 rows

typedef __attribute__((ext_vector_type(8))) short   short8;
typedef __attribute__((ext_vector_type(4))) float   float4v;
typedef __attribute__((ext_vector_type(4))) int     int4v;
typedef __attribute__((ext_vector_type(2))) int     int2v;

__device__ __forceinline__ float b2f(unsigned short u) {
    unsigned int x = ((unsigned int)u) << 16;
    return __builtin_bit_cast(float, x);
}
__device__ __forceinline__ unsigned short f2b(float f) {
    unsigned int x = __builtin_bit_cast(unsigned int, f);
    x += 0x7fffu + ((x >> 16) & 1u);   // round-to-nearest-even
    return (unsigned short)(x >> 16);
}
__device__ __forceinline__ int pack2(float lo, float hi) {
    return (int)f2b(lo) | ((int)f2b(hi) << 16);
}
__device__ __forceinline__ float sigmoid_f(float x) {
    return 1.f / (1.f + __expf(-x));
}
__device__ __forceinline__ float tanh_f(float x) {
    return 1.f - 2.f / (__expf(2.f * x) + 1.f);  // safe at exp overflow
}

// async global -> LDS, 16B per lane (wave-uniform LDS base; HW adds lane*16)
__device__ __forceinline__ void gload_lds16(const void* g, void* l) {
    __builtin_amdgcn_global_load_lds(
        (const __attribute__((address_space(1))) void*)g,
        (__attribute__((address_space(3))) void*)l, 16, 0, 0);
}

// ---------------------------------------------------------------------------
// Gate kernel: e = sigmoid(X We^T + be), a = tanh(X Wa^T + ba)
// X: (M_,256) fp32. We/Wa: (256,256) fp32 row-major [out][in] = B^T layout.
// Outputs bf16. grid (M_/128, 2, 2)  block 256
// ---------------------------------------------------------------------------
__global__ __launch_bounds__(256) void gate_kernel(
    const float* __restrict__ X,
    const float* __restrict__ We, const float* __restrict__ be,
    const float* __restrict__ Wa, const float* __restrict__ ba,
    unsigned short* __restrict__ e_out, unsigned short* __restrict__ a_out)
{
    constexpr int K = DV_;  // 256
    const int mblk = blockIdx.x, nblk = blockIdx.y, gate = blockIdx.z;
    const float* W    = gate ? Wa : We;
    const float* bias = gate ? ba : be;
    unsigned short* out = gate ? a_out : e_out;

    __shared__ unsigned short As[128 * 40];  // +8 pad per row
    __shared__ unsigned short Bs[128 * 40];

    const int tid  = threadIdx.x;
    const int lane = tid & 63, wid = tid >> 6;
    const int wm = wid >> 1, wn = wid & 1;
    const int l15 = lane & 15, quad = lane >> 4;

    float4v acc[4][4];
#pragma unroll
    for (int i = 0; i < 4; i++)
#pragma unroll
        for (int j = 0; j < 4; j++) {
            acc[i][j][0] = 0.f; acc[i][j][1] = 0.f;
            acc[i][j][2] = 0.f; acc[i][j][3] = 0.f;
        }

    const int srow = tid >> 1;          // 0..127
    const int scol = (tid & 1) * 16;    // 0 or 16 (bf16 element units)
    const size_t Abase = ((size_t)mblk * 128 + srow) * K;
    const size_t Bbase = ((size_t)nblk * 128 + srow) * K;

    for (int k0 = 0; k0 < K; k0 += 32) {
        const float* xa = &X[Abase + k0 + scol];
        const float* xb = &W[Bbase + k0 + scol];
        // vectorized fp32 loads (dwordx4), then pack to bf16
        float4v va0 = *(const float4v*)(xa);
        float4v va1 = *(const float4v*)(xa + 4);
        float4v va2 = *(const float4v*)(xa + 8);
        float4v va3 = *(const float4v*)(xa + 12);
        float4v vb0 = *(const float4v*)(xb);
        float4v vb1 = *(const float4v*)(xb + 4);
        float4v vb2 = *(const float4v*)(xb + 8);
        float4v vb3 = *(const float4v*)(xb + 12);
        int4v pa0, pa1, pb0, pb1;
        pa0[0] = pack2(va0[0], va0[1]); pa0[1] = pack2(va0[2], va0[3]);
        pa0[2] = pack2(va1[0], va1[1]); pa0[3] = pack2(va1[2], va1[3]);
        pa1[0] = pack2(va2[0], va2[1]); pa1[1] = pack2(va2[2], va2[3]);
        pa1[2] = pack2(va3[0], va3[1]); pa1[3] = pack2(va3[2], va3[3]);
        pb0[0] = pack2(vb0[0], vb0[1]); pb0[1] = pack2(vb0[2], vb0[3]);
        pb0[2] = pack2(vb1[0], vb1[1]); pb0[3] = pack2(vb1[2], vb1[3]);
        pb1[0] = pack2(vb2[0], vb2[1]); pb1[1] = pack2(vb2[2], vb2[3]);
        pb1[2] = pack2(vb3[0], vb3[1]); pb1[3] = pack2(vb3[2], vb3[3]);
        *(int4v*)&As[srow * 40 + scol]     = pa0;
        *(int4v*)&As[srow * 40 + scol + 8] = pa1;
        *(int4v*)&Bs[srow * 40 + scol]     = pb0;
        *(int4v*)&Bs[srow * 40 + scol + 8] = pb1;
        __syncthreads();
        short8 af[4], bf[4];
#pragma unroll
        for (int i = 0; i < 4; i++)
            af[i] = *(const short8*)&As[(64 * wm + 16 * i + l15) * 40 + quad * 8];
#pragma unroll
        for (int j = 0; j < 4; j++)
            bf[j] = *(const short8*)&Bs[(64 * wn + 16 * j + l15) * 40 + quad * 8];
#pragma unroll
        for (int i = 0; i < 4; i++)
#pragma unroll
            for (int j = 0; j < 4; j++)
                acc[i][j] = __builtin_amdgcn_mfma_f32_16x16x32_bf16(af[i], bf[j], acc[i][j], 0, 0, 0);
        __syncthreads();
    }

#pragma unroll
    for (int i = 0; i < 4; i++) {
        const int row = mblk * 128 + 64 * wm + 16 * i + quad * 4;
#pragma unroll
        for (int j = 0; j < 4; j++) {
            const int col = nblk * 128 + 64 * wn + 16 * j + l15;
            const float bv = bias[col];
#pragma unroll
            for (int r = 0; r < 4; r++) {
                float v = acc[i][j][r] + bv;
                v = gate ? tanh_f(v) : sigmoid_f(v);
                out[(size_t)(row + r) * DV_ + col] = f2b(v);
            }
        }
    }
}

// ---------------------------------------------------------------------------
// Score kernel: score = softmax(P Wk^T) over 50 slots. Thread per row. fp32.
// Grouped layout for the scan: (M_,64) fp32; slot n = g*13+i stored at
// position [g*16 + i] for i<13 and n<50; other positions zero.
// grid 512, block 256
// ---------------------------------------------------------------------------
__global__ __launch_bounds__(256) void score_kernel(
    const float* __restrict__ problems,  // (M_,128)
    const float* __restrict__ w_key,     // (50,128)
    float* __restrict__ score_scan)      // (M_,64)
{
    const int rowi = blockIdx.x * 256 + threadIdx.x;
    const float* p = problems + (size_t)rowi * DK_;

    float logit[NS_];
#pragma unroll
    for (int n = 0; n < NS_; n++) logit[n] = 0.f;

    for (int k0 = 0; k0 < DK_; k0 += 4) {
        float pf0 = p[k0], pf1 = p[k0+1], pf2 = p[k0+2], pf3 = p[k0+3];
#pragma unroll
        for (int n = 0; n < NS_; n++) {
            const float* wk = &w_key[n * DK_ + k0];   // wave-uniform -> s_load
            logit[n] += pf0 * wk[0] + pf1 * wk[1] + pf2 * wk[2] + pf3 * wk[3];
        }
    }

    float mx = logit[0];
#pragma unroll
    for (int n = 1; n < NS_; n++) mx = fmaxf(mx, logit[n]);
    float sum = 0.f;
#pragma unroll
    for (int n = 0; n < NS_; n++) { logit[n] = __expf(logit[n] - mx); sum += logit[n]; }
    const float inv = 1.f / sum;

    float* o = score_scan + (size_t)rowi * 64;
#pragma unroll
    for (int v = 0; v < 16; v++) {
        float4v st;
#pragma unroll
        for (int c = 0; c < 4; c++) {
            const int j  = v * 4 + c;
            const int ng = j >> 4, ii = j & 15;
            const int n  = ng * 13 + ii;
            st[c] = (ii < 13 && n < NS_) ? logit[n] * inv : 0.f;
        }
        *(float4v*)(o + v * 4) = st;
    }
}

// ---------------------------------------------------------------------------
// Scan kernel v5: slot-groups per WAVE (wave w owns slots 13w..13w+12, all
// 64 lanes = 64 d-columns). s values are wave-uniform -> SMEM (s_load) with
// distance-2 SGPR pipeline; DS pipe only carries e/a (2x u16) and the
// partial-read staging (1x b32 write + amortized b128 reduce every 16 t).
// e/a chunk-staged via global_load_lds, double-buffered.
// LDS: e/a 2x2x16KB + r_s 16KB = 80 KB -> 2 blocks/CU.
// grid (4, 128)  block 256.
// ---------------------------------------------------------------------------
#define TCH 128          // e/a chunk timesteps
#define NCH (L_ / TCH)   // 8
#define RCH 16           // partial-read reduce subchunk

__global__ __launch_bounds__(256, 2) void scan_kernel(
    const float* __restrict__ score_scan,         // (M_,64) fp32, grouped+padded
    const unsigned short* __restrict__ e_buf,     // (M_,256) bf16
    const unsigned short* __restrict__ a_buf,     // (M_,256) bf16
    const float* __restrict__ init_mem,           // (50,256) fp32
    unsigned short* __restrict__ reads)           // (M_,256) bf16
{
    __shared__ unsigned short e_s[2][TCH][64];   // 2 x 16 KB
    __shared__ unsigned short a_s[2][TCH][64];   // 2 x 16 KB
    __shared__ float          r_s[4][RCH][64];   // 16 KB

    const int b    = blockIdx.y;
    const int dblk = blockIdx.x;          // 0..3
    const int tid  = threadIdx.x;
    const int w    = tid >> 6;            // wave id = slot group 0..3
    const int lane = tid & 63;            // d sub-index
    const int d    = dblk * 64 + lane;

    float M[13];
#pragma unroll
    for (int i = 0; i < 13; i++) {
        const int n = w * 13 + i;
        M[i] = (n < NS_) ? init_mem[n * DV_ + d] : 0.f;
    }

    const size_t rb = (size_t)b * L_;
    const float* srow = score_scan + rb * 64 + w * 16;   // wave-uniform base

    auto stage = [&](int c, int p) {
        const int t0 = c * TCH;
#pragma unroll
        for (int i = 0; i < 4; i++) {
            const int r0 = w * 32 + i * 8;               // 8 rows per inst
            const int tt = t0 + r0 + (lane >> 3);
            const size_t goff = (rb + tt) * (size_t)DV_ + dblk * 64 + (lane & 7) * 8;
            gload_lds16(e_buf + goff, &e_s[p][r0][0]);
            gload_lds16(a_buf + goff, &a_s[p][r0][0]);
        }
    };

    // s pipeline (wave-uniform -> SGPRs), distance 2
    float4v sc0, sc1, sc2; float sc3;
    float4v sn0, sn1, sn2; float sn3;
    auto loadS = [&](int t, float4v& x0, float4v& x1, float4v& x2, float& x3) {
        const float* sp = srow + (size_t)t * 64;
        x0 = *(const float4v*)(sp);
        x1 = *(const float4v*)(sp + 4);
        x2 = *(const float4v*)(sp + 8);
        x3 = sp[12];
    };

    int pp = 0;
    stage(0, 0);
    loadS(0, sc0, sc1, sc2, sc3);
    loadS(1, sn0, sn1, sn2, sn3);
    asm volatile("s_waitcnt vmcnt(0)" ::: "memory");
    __syncthreads();

    for (int c = 0; c < NCH; ++c) {
        if (c + 1 < NCH) stage(c + 1, pp ^ 1);   // in flight during compute

        for (int sub = 0; sub < TCH / RCH; ++sub) {
            const int tbase = c * TCH + sub * RCH;
            const int lbase = sub * RCH;          // e/a row base within chunk
#pragma unroll
            for (int u = 0; u < RCH; u += 2) {
                {   // t = tbase + u  (uses sc*)
                    const float e_cur = b2f(e_s[pp][lbase + u][lane]);
                    const float a_cur = b2f(a_s[pp][lbase + u][lane]);
                    float r = 0.f;
                    const float sarr[13] = { sc0[0], sc0[1], sc0[2], sc0[3],
                                             sc1[0], sc1[1], sc1[2], sc1[3],
                                             sc2[0], sc2[1], sc2[2], sc2[3], sc3 };
#pragma unroll
                    for (int i = 0; i < 13; i++) {
                        const float s = sarr[i];
                        r = fmaf(s, M[i], r);                       // read BEFORE update
                        M[i] = fmaf(s, fmaf(-e_cur, M[i], a_cur), M[i]);
                    }
                    r_s[w][u][lane] = r;
                    const int tl = tbase + u + 2;
                    loadS(tl < L_ ? tl : L_ - 1, sc0, sc1, sc2, sc3);
                }
                {   // t = tbase + u + 1  (uses sn*)
                    const float e_cur = b2f(e_s[pp][lbase + u + 1][lane]);
                    const float a_cur = b2f(a_s[pp][lbase + u + 1][lane]);
                    float r = 0.f;
                    const float sarr[13] = { sn0[0], sn0[1], sn0[2], sn0[3],
                                             sn1[0], sn1[1], sn1[2], sn1[3],
                                             sn2[0], sn2[1], sn2[2], sn2[3], sn3 };
#pragma unroll
                    for (int i = 0; i < 13; i++) {
                        const float s = sarr[i];
                        r = fmaf(s, M[i], r);
                        M[i] = fmaf(s, fmaf(-e_cur, M[i], a_cur), M[i]);
                    }
                    r_s[w][u + 1][lane] = r;
                    const int tl = tbase + u + 3;
                    loadS(tl < L_ ? tl : L_ - 1, sn0, sn1, sn2, sn3);
                }
            }
            __syncthreads();
            {   // reduce partials across the 4 waves, store 16 t of reads
                const int tt = tid >> 4;          // 0..15
                const int d0 = (tid & 15) * 4;    // 0,4,...,60
                float4v v0 = *(const float4v*)&r_s[0][tt][d0];
                float4v v1 = *(const float4v*)&r_s[1][tt][d0];
                float4v v2 = *(const float4v*)&r_s[2][tt][d0];
                float4v v3 = *(const float4v*)&r_s[3][tt][d0];
                float4v sm = (v0 + v1) + (v2 + v3);
                int2v pk;
                pk[0] = pack2(sm[0], sm[1]);
                pk[1] = pack2(sm[2], sm[3]);
                *(int2v*)&reads[(rb + tbase + tt) * (size_t)DV_ + dblk * 64 + d0] = pk;
            }
            __syncthreads();   // r_s free for next sub
        }

        asm volatile("s_waitcnt vmcnt(0)" ::: "memory");  // next chunk landed
        __syncthreads();
        pp ^= 1;
    }
}

// ---------------------------------------------------------------------------
// Output kernel: out = tanh([reads | problems] Wo^T + bo), fp32 out
// K = 384 (256 reads bf16 + 128 problems fp32). grid (M_/128, 2) block 256
// ---------------------------------------------------------------------------
__global__ __launch_bounds__(256) void out_kernel(
    const unsigned short* __restrict__ reads,  // (M_,256) bf16
    const float* __restrict__ problems,        // (M_,128) fp32
    const float* __restrict__ Wo,              // (256,384) fp32
    const float* __restrict__ bo,              // (256) fp32
    float* __restrict__ out)                   // (M_,256) fp32
{
    constexpr int K = DV_ + DK_;  // 384
    const int mblk = blockIdx.x, nblk = blockIdx.y;

    __shared__ unsigned short As[128 * 40];
    __shared__ unsigned short Bs[128 * 40];

    const int tid  = threadIdx.x;
    const int lane = tid & 63, wid = tid >> 6;
    const int wm = wid >> 1, wn = wid & 1;
    const int l15 = lane & 15, quad = lane >> 4;

    float4v acc[4][4];
#pragma unroll
    for (int i = 0; i < 4; i++)
#pragma unroll
        for (int j = 0; j < 4; j++) {
            acc[i][j][0] = 0.f; acc[i][j][1] = 0.f;
            acc[i][j][2] = 0.f; acc[i][j][3] = 0.f;
        }

    const int srow = tid >> 1;
    const int scol = (tid & 1) * 16;
    const size_t mrow = (size_t)mblk * 128 + srow;
    const size_t brow = (size_t)nblk * 128 + srow;

    for (int k0 = 0; k0 < K; k0 += 32) {
        const int kk = k0 + scol;
        int4v a0, a1;
        if (kk < DV_) {  // reads, already bf16
            a0 = *(const int4v*)&reads[mrow * DV_ + kk];
            a1 = *(const int4v*)&reads[mrow * DV_ + kk + 8];
        } else {         // problems, fp32 -> bf16 (vectorized loads)
            const float* pr = &problems[mrow * DK_ + (kk - DV_)];
            float4v v0 = *(const float4v*)(pr);
            float4v v1 = *(const float4v*)(pr + 4);
            float4v v2 = *(const float4v*)(pr + 8);
            float4v v3 = *(const float4v*)(pr + 12);
            a0[0] = pack2(v0[0], v0[1]); a0[1] = pack2(v0[2], v0[3]);
            a0[2] = pack2(v1[0], v1[1]); a0[3] = pack2(v1[2], v1[3]);
            a1[0] = pack2(v2[0], v2[1]); a1[1] = pack2(v2[2], v2[3]);
            a1[2] = pack2(v3[0], v3[1]); a1[3] = pack2(v3[2], v3[3]);
        }
        const float* wb = &Wo[brow * K + kk];
        float4v u0 = *(const float4v*)(wb);
        float4v u1 = *(const float4v*)(wb + 4);
        float4v u2 = *(const float4v*)(wb + 8);
        float4v u3 = *(const float4v*)(wb + 12);
        int4v b0, b1;
        b0[0] = pack2(u0[0], u0[1]); b0[1] = pack2(u0[2], u0[3]);
        b0[2] = pack2(u1[0], u1[1]); b0[3] = pack2(u1[2], u1[3]);
        b1[0] = pack2(u2[0], u2[1]); b1[1] = pack2(u2[2], u2[3]);
        b1[2] = pack2(u3[0], u3[1]); b1[3] = pack2(u3[2], u3[3]);
        *(int4v*)&As[srow * 40 + scol]     = a0;
        *(int4v*)&As[srow * 40 + scol + 8] = a1;
        *(int4v*)&Bs[srow * 40 + scol]     = b0;
        *(int4v*)&Bs[srow * 40 + scol + 8] = b1;
        __syncthreads();
        short8 af[4], bf[4];
#pragma unroll
        for (int i = 0; i < 4; i++)
            af[i] = *(const short8*)&As[(64 * wm + 16 * i + l15) * 40 + quad * 8];
#pragma unroll
        for (int j = 0; j < 4; j++)
            bf[j] = *(const short8*)&Bs[(64 * wn + 16 * j + l15) * 40 + quad * 8];
#pragma unroll
        for (int i = 0; i < 4; i++)
#pragma unroll
            for (int j = 0; j < 4; j++)
                acc[i][j] = __builtin_amdgcn_mfma_f32_16x16x32_bf16(af[i], bf[j], acc[i][j], 0, 0, 0);
        __syncthreads();
    }

#pragma unroll
    for (int i = 0; i < 4; i++) {
        const int row = mblk * 128 + 64 * wm + 16 * i + quad * 4;
#pragma unroll
        for (int j = 0; j < 4; j++) {
            const int col = nblk * 128 + 64 * wn + 16 * j + l15;
            const float bv = bo[col];
#pragma unroll
            for (int r = 0; r < 4; r++) {
                out[(size_t)(row + r) * H_ + col] = tanh_f(acc[i][j][r] + bv);
            }
        }
    }
}

// ---------------------------------------------------------------------------
extern "C" void kernel_launch(void* const* d_in, const int* in_sizes, int n_in,
                              void* d_out, int out_size, void* d_ws, size_t ws_size,
                              hipStream_t stream) {
    const float* problems  = (const float*)d_in[0];
    const float* interact  = (const float*)d_in[1];
    const float* w_key     = (const float*)d_in[2];
    const float* w_erase_w = (const float*)d_in[3];
    const float* w_erase_b = (const float*)d_in[4];
    const float* w_add_w   = (const float*)d_in[5];
    const float* w_add_b   = (const float*)d_in[6];
    const float* w_out_w   = (const float*)d_in[7];
    const float* w_out_b   = (const float*)d_in[8];
    const float* init_mem  = (const float*)d_in[9];

    // workspace: e (64MB bf16) | a (64MB bf16) | reads (64MB bf16) | score_scan (33.5MB fp32)
    char* ws = (char*)d_ws;
    const size_t SZ_BF = (size_t)M_ * DV_ * 2;   // 67,108,864
    unsigned short* e_buf = (unsigned short*)(ws);
    unsigned short* a_buf = (unsigned short*)(ws + SZ_BF);
    unsigned short* reads = (unsigned short*)(ws + 2 * SZ_BF);
    float*     score_scan = (float*)(ws + 3 * SZ_BF);

    gate_kernel<<<dim3(M_ / 128, DV_ / 128, 2), 256, 0, stream>>>(
        interact, w_erase_w, w_erase_b, w_add_w, w_add_b, e_buf, a_buf);

    score_kernel<<<M_ / 256, 256, 0, stream>>>(problems, w_key, score_scan);

    scan_kernel<<<dim3(4, B_), 256, 0, stream>>>(
        score_scan, e_buf, a_buf, init_mem, reads);

    out_kernel<<<dim3(M_ / 128, H_ / 128), 256, 0, stream>>>(
        reads, problems, w_out_w, w_out_b, (float*)d_out);
}